// Round 7
// baseline (518.570 us; speedup 1.0000x reference)
//
#include <hip/hip_runtime.h>
#include <hip/hip_fp16.h>
#include <cmath>

// ---------------------------------------------------------------------------
// Self_Attention: B=8, C=256, C_=32, H=W=64, N=4096, GAMMA=1.0
// R7: barrier-free pass2 with NO exp redundancy (full-c 32ix256c blocks) and
// x32 O-GEMM via j-interleaved gt row permutation: within each 32-j window,
// storage rows [0..15] hold true j {8q'+r}, rows [16..31] hold {8q'+4+r}.
// Then two S^T D-frags per lane = exactly the B-operand (k=8q+e) of
// mfma_f32_16x16x32_f16 -> O-GEMM at full K, h A-frags are b128.
// pass1 remaps output index; linv stored in true-j order.
// proj unified: one block per (b, 64-pix tile), xt tile staged in LDS once,
// computes f, g (permuted rows), h together.
// ws: xt 16M (l4 aliases after proj) | wf | ft 2M | gt 2M | hm 16M | linv
// ---------------------------------------------------------------------------

#define BN 8
#define CC 256
#define CQ 32
#define NN 4096

typedef _Float16 half8 __attribute__((ext_vector_type(8)));
typedef _Float16 half4v __attribute__((ext_vector_type(4)));
typedef float f32x4 __attribute__((ext_vector_type(4)));

static __device__ __forceinline__ float fexp2(float x) {
    return __builtin_amdgcn_exp2f(x);
}

#define LOG2E 1.44269504f

// storage row (within 32-window) for true pixel offset pw
static __device__ __forceinline__ int perm_store(int pw) {
    return ((pw & 4) ? 16 : 0) + 4 * (pw >> 3) + (pw & 3);
}

// --------------------------------------------------------------------------
// K0: weight conversion f32 -> f16.
// --------------------------------------------------------------------------
__global__ __launch_bounds__(256) void cvtw_kernel(
    const float* __restrict__ fw, const float* __restrict__ gw,
    const float* __restrict__ hw, __half* __restrict__ wf16)
{
    int i = blockIdx.x * 256 + threadIdx.x;
    float v;
    if (i < 8192)       v = fw[i];
    else if (i < 16384) v = gw[i - 8192];
    else                v = hw[i - 16384];
    wf16[i] = __float2half(v);
}

// --------------------------------------------------------------------------
// K1: transpose + cvt x[b][c][n] f32 -> xt[b][n][c] f16.  64n x 64c tiles.
// --------------------------------------------------------------------------
__global__ __launch_bounds__(256) void transpose_kernel(
    const float* __restrict__ x, __half* __restrict__ xt)
{
    const int gid = blockIdx.x;
    const int b = gid & 7, rest = gid >> 3;
    const int n0 = (rest & 63) * 64;
    const int c0 = (rest >> 6) * 64;
    const int tid = threadIdx.x;

    __shared__ float T[64 * 65];

    const float* xb = x + ((size_t)b * CC + c0) * NN + n0;
    const int u  = tid >> 4;
    const int n4 = (tid & 15) * 4;
#pragma unroll
    for (int r = 0; r < 4; ++r) {
        int c = r * 16 + u;
        f32x4 v = __builtin_nontemporal_load((const f32x4*)(xb + (size_t)c * NN + n4));
        T[c * 65 + n4 + 0] = v.x;
        T[c * 65 + n4 + 1] = v.y;
        T[c * 65 + n4 + 2] = v.z;
        T[c * 65 + n4 + 3] = v.w;
    }
    __syncthreads();

    const int lane = tid & 63, w = tid >> 6;
    const int n  = w * 16 + (lane >> 2);
    const int cc = (lane & 3) * 16;
    half8 o0, o1;
#pragma unroll
    for (int k = 0; k < 8; ++k) {
        o0[k] = (_Float16)T[(cc + k) * 65 + n];
        o1[k] = (_Float16)T[(cc + 8 + k) * 65 + n];
    }
    __half* dst = xt + ((size_t)b * NN + n0 + n) * CC + c0 + cc;
    *(half8*)(void*)dst = o0;
    *(half8*)(void*)(dst + 8) = o1;
}

// --------------------------------------------------------------------------
// K2: unified projections. 1D grid 512: b = gid&7, nt = gid>>3 (64 pix).
// Stage xt tile (64 pix x 256 c, pitch 264) in LDS once; each wave owns a
// 16-pix tile and computes: f/g (A=W, B=xt -> D[c_out][pix], f scaled by
// LOG2E, gt rows stored permuted) and h (A=xt, B=Wh -> D[pix][c_out], b64
// stores along pix).
// --------------------------------------------------------------------------
__global__ __launch_bounds__(256) void proj_kernel(
    const __half* __restrict__ xt, const __half* __restrict__ wf16,
    const float* __restrict__ fb, const float* __restrict__ gb,
    const float* __restrict__ hb,
    __half* __restrict__ ft, __half* __restrict__ gt, __half* __restrict__ hm)
{
    const int tid = threadIdx.x;
    const int w = tid >> 6, lane = tid & 63, col = lane & 15, q = lane >> 4;
    const int gid = blockIdx.x;
    const int b = gid & 7;
    const int n0 = (gid >> 3) * 64;

    __shared__ __half xs[64 * 264];

    const __half* xtb  = xt + (size_t)b * NN * CC;
    const __half* hw16 = wf16 + 16384;

    // stage 32 KB: 2048 half8 chunks, 8 per thread
#pragma unroll
    for (int k = 0; k < 8; ++k) {
        int id = tid + 256 * k;
        int row = id >> 5, kc = id & 31;
        half8 v = *(const half8*)(const void*)(xtb + (size_t)(n0 + row) * CC + kc * 8);
        *(half8*)(void*)(&xs[row * 264 + kc * 8]) = v;
    }
    __syncthreads();

    // this wave's xt frags (pix = 16w+col), k = ks*32 + q*8
    half8 xf[8];
#pragma unroll
    for (int ks = 0; ks < 8; ++ks)
        xf[ks] = *(const half8*)(const void*)(&xs[(16 * w + col) * 264 + ks * 32 + q * 8]);

    const f32x4 zero = {0.f, 0.f, 0.f, 0.f};
    const int pix = n0 + 16 * w + col;

    // ---- f / g ----
    {
        f32x4 afg[4];
#pragma unroll
        for (int mt = 0; mt < 4; ++mt) afg[mt] = zero;
#pragma unroll
        for (int ks = 0; ks < 8; ++ks) {
#pragma unroll
            for (int mt = 0; mt < 4; ++mt) {
                const __half* wp = wf16 + (mt < 2 ? 0 : 8192);
                half8 wfr = *(const half8*)(const void*)(
                    wp + (16 * (mt & 1) + col) * CC + ks * 32 + q * 8);
                afg[mt] = __builtin_amdgcn_mfma_f32_16x16x32_f16(wfr, xf[ks], afg[mt], 0, 0, 0);
            }
        }
#pragma unroll
        for (int mt = 0; mt < 4; ++mt) {
            const int mtl = mt & 1;
            const float* bsel = (mt < 2) ? fb : gb;
            const float scale = (mt < 2) ? LOG2E : 1.0f;
            half4v hv;
#pragma unroll
            for (int r = 0; r < 4; ++r)
                hv[r] = (_Float16)((afg[mt][r] + bsel[16 * mtl + 4 * q + r]) * scale);
            if (mt < 2) {
                *(half4v*)(void*)(ft + ((size_t)b * NN + pix) * CQ + 16 * mtl + 4 * q) = hv;
            } else {
                int srow = (pix & ~31) | perm_store(pix & 31);
                *(half4v*)(void*)(gt + ((size_t)b * NN + srow) * CQ + 16 * mtl + 4 * q) = hv;
            }
        }
    }

    // ---- h ----  (pairs of c_out tiles for ILP)
#pragma unroll
    for (int ntp = 0; ntp < 8; ++ntp) {
        const int nt0 = 2 * ntp, nt1 = 2 * ntp + 1;
        f32x4 h0 = zero, h1 = zero;
#pragma unroll
        for (int ks = 0; ks < 8; ++ks) {
            half8 w0 = *(const half8*)(const void*)(
                hw16 + (16 * nt0 + col) * CC + ks * 32 + q * 8);
            half8 w1 = *(const half8*)(const void*)(
                hw16 + (16 * nt1 + col) * CC + ks * 32 + q * 8);
            h0 = __builtin_amdgcn_mfma_f32_16x16x32_f16(xf[ks], w0, h0, 0, 0, 0);
            h1 = __builtin_amdgcn_mfma_f32_16x16x32_f16(xf[ks], w1, h1, 0, 0, 0);
        }
        const float bias0 = hb[16 * nt0 + col];
        const float bias1 = hb[16 * nt1 + col];
        half4v o0, o1;
#pragma unroll
        for (int r = 0; r < 4; ++r) {
            o0[r] = (_Float16)(h0[r] + bias0);
            o1[r] = (_Float16)(h1[r] + bias1);
        }
        *(half4v*)(void*)(hm + ((size_t)b * CC + 16 * nt0 + col) * NN + n0 + 16 * w + 4 * q) = o0;
        *(half4v*)(void*)(hm + ((size_t)b * CC + 16 * nt1 + col) * NN + n0 + 16 * w + 4 * q) = o1;
    }
}

// --------------------------------------------------------------------------
// K3: partial softmax denominators over an i-quarter. gt rows are permuted,
// so the column this lane sums belongs to true j -> remap at store.
// 1D grid 2048: b = gid&7, jt = (gid>>3)&63, part = gid>>9.
// --------------------------------------------------------------------------
__global__ __launch_bounds__(256) void pass1_kernel(
    const __half* __restrict__ ft, const __half* __restrict__ gt,
    float* __restrict__ l4)
{
    const int tid = threadIdx.x;
    const int w = tid >> 6, lane = tid & 63, col = lane & 15, q = lane >> 4;
    const int gid = blockIdx.x;
    const int b = gid & 7;
    const int jg = ((gid >> 3) & 63) * 64 + 16 * w + col;   // storage row
    const int part = gid >> 9;
    const int ib = part * 1024;

    const __half* fbase = ft + (size_t)b * NN * CQ;
    half8 gfrag = *(const half8*)(const void*)(gt + ((size_t)b * NN + jg) * CQ + q * 8);

    float a0 = 0.f, a1 = 0.f, a2 = 0.f, a3 = 0.f;
    float b0 = 0.f, b1 = 0.f, b2 = 0.f, b3 = 0.f;
    const f32x4 zero = {0.f, 0.f, 0.f, 0.f};

    half8 aA = *(const half8*)(const void*)(fbase + (size_t)(ib + col) * CQ + q * 8);
    half8 aB = *(const half8*)(const void*)(fbase + (size_t)(ib + 16 + col) * CQ + q * 8);
    for (int i0 = ib; i0 < ib + 1024; i0 += 32) {
        int i_n = (i0 + 32) & (NN - 1);
        half8 aA2 = *(const half8*)(const void*)(fbase + (size_t)(i_n + col) * CQ + q * 8);
        half8 aB2 = *(const half8*)(const void*)(fbase + (size_t)(i_n + 16 + col) * CQ + q * 8);
        f32x4 d0 = __builtin_amdgcn_mfma_f32_16x16x32_f16(aA, gfrag, zero, 0, 0, 0);
        f32x4 d1 = __builtin_amdgcn_mfma_f32_16x16x32_f16(aB, gfrag, zero, 0, 0, 0);
        a0 += fexp2(d0[0]); a1 += fexp2(d0[1]); a2 += fexp2(d0[2]); a3 += fexp2(d0[3]);
        b0 += fexp2(d1[0]); b1 += fexp2(d1[1]); b2 += fexp2(d1[2]); b3 += fexp2(d1[3]);
        aA = aA2; aB = aB2;
    }
    float l = ((a0 + a1) + (a2 + a3)) + ((b0 + b1) + (b2 + b3));
    l += __shfl_xor(l, 16);
    l += __shfl_xor(l, 32);
    if (q == 0) {
        int m = jg & 31;   // storage row -> true j within window
        int tj = (jg & ~31) + 8 * ((m & 15) >> 2) + (m & 3) + ((m & 16) ? 4 : 0);
        l4[(size_t)part * (BN * NN) + (size_t)b * NN + tj] = l;
    }
}

// --------------------------------------------------------------------------
// K3b: linv = 1 / (sum of 4 partials).
// --------------------------------------------------------------------------
__global__ __launch_bounds__(256) void linv_kernel(
    const float* __restrict__ l4, float* __restrict__ linv)
{
    int i = blockIdx.x * 256 + threadIdx.x;
    float s = l4[i] + l4[BN * NN + i] + l4[2 * BN * NN + i] + l4[3 * BN * NN + i];
    linv[i] = 1.f / s;
}

// --------------------------------------------------------------------------
// K4: O = h @ P^T + x, barrier-free, no exp redundancy, x32 O-GEMM.
// 1D grid 1024: b = gid&7, i-block = gid>>3 -> 32 i x 256 c.
// Wave w, step s: j-window W = 128s+32w (32 j).  Two S^T x32 MFMAs per
// i-tile (permuted-gt A rows) give lane j = W+8q+{0..7} = exactly the
// k=8q+e B-operand of the x32 O-GEMM.  P = exp2(S')*linv in-register.
// h A-frags: b128 direct from hm (L2-resident).  End: LDS reduce + x + out.
// --------------------------------------------------------------------------
__global__ __launch_bounds__(256, 2) void pass2_kernel(
    const float* __restrict__ x,
    const __half* __restrict__ ft, const __half* __restrict__ gt,
    const __half* __restrict__ hm, const float* __restrict__ linv,
    float* __restrict__ out)
{
    const int tid = threadIdx.x;
    const int w = tid >> 6, lane = tid & 63, col = lane & 15, q = lane >> 4;
    const int gid = blockIdx.x;
    const int b  = gid & 7;
    const int i0 = (gid >> 3) * 32;

    __shared__ float red[256 * 36];   // [c][i], 36 KB

    const __half* gbase = gt + (size_t)b * NN * CQ;
    const __half* hbase = hm + (size_t)b * CC * NN;
    const float*  lb    = linv + (size_t)b * NN;

    // loop-invariant f B-frags (n = i), i-tiles it = 0,1
    half8 ffr[2];
#pragma unroll
    for (int it = 0; it < 2; ++it)
        ffr[it] = *(const half8*)(const void*)(
            ft + ((size_t)b * NN + i0 + 16 * it + col) * CQ + q * 8);

    f32x4 acc[2][16];
#pragma unroll
    for (int it = 0; it < 2; ++it)
#pragma unroll
        for (int ct = 0; ct < 16; ++ct)
            acc[it][ct] = (f32x4){0.f, 0.f, 0.f, 0.f};

    const f32x4 zero = {0.f, 0.f, 0.f, 0.f};

    // prologue: gt A-frags for step 0 (storage rows W..W+31, natural order)
    int W = 32 * w;
    half8 g1 = *(const half8*)(const void*)(gbase + (size_t)(W + col) * CQ + q * 8);
    half8 g2 = *(const half8*)(const void*)(gbase + (size_t)(W + 16 + col) * CQ + q * 8);

    for (int s = 0; s < 32; ++s) {
        W = 128 * s + 32 * w;

        // h A-frags, first 8 c-tiles (k = j = W+8q+e -> b128)
        half8 hA[8];
#pragma unroll
        for (int ct = 0; ct < 8; ++ct)
            hA[ct] = *(const half8*)(const void*)(
                hbase + (size_t)(16 * ct + col) * NN + W + 8 * q);

        // S'^T: d[t][it]; lane holds j = W + 8q + r (t=0) / W + 8q + 4 + r (t=1)
        f32x4 d00 = __builtin_amdgcn_mfma_f32_16x16x32_f16(g1, ffr[0], zero, 0, 0, 0);
        f32x4 d10 = __builtin_amdgcn_mfma_f32_16x16x32_f16(g2, ffr[0], zero, 0, 0, 0);
        f32x4 d01 = __builtin_amdgcn_mfma_f32_16x16x32_f16(g1, ffr[1], zero, 0, 0, 0);
        f32x4 d11 = __builtin_amdgcn_mfma_f32_16x16x32_f16(g2, ffr[1], zero, 0, 0, 0);

        // next-step gt prefetch
        const int Wn = ((128 * (s + 1)) & (NN - 1)) + 32 * w;
        half8 g1n = *(const half8*)(const void*)(gbase + (size_t)(Wn + col) * CQ + q * 8);
        half8 g2n = *(const half8*)(const void*)(gbase + (size_t)(Wn + 16 + col) * CQ + q * 8);

        // linv, true-j order, contiguous
        f32x4 il0 = *(const f32x4*)(lb + W + 8 * q);
        f32x4 il1 = *(const f32x4*)(lb + W + 8 * q + 4);

        // P fragments (B-operand of x32): pv[it][e] , e = k offset 0..7
        half8 pv0, pv1;
#pragma unroll
        for (int e = 0; e < 4; ++e) {
            pv0[e]     = (_Float16)(fexp2(d00[e]) * il0[e]);
            pv0[4 + e] = (_Float16)(fexp2(d10[e]) * il1[e]);
            pv1[e]     = (_Float16)(fexp2(d01[e]) * il0[e]);
            pv1[4 + e] = (_Float16)(fexp2(d11[e]) * il1[e]);
        }

        // h A-frags, second 8 c-tiles
        half8 hB[8];
#pragma unroll
        for (int ct = 0; ct < 8; ++ct)
            hB[ct] = *(const half8*)(const void*)(
                hbase + (size_t)(16 * (8 + ct) + col) * NN + W + 8 * q);

        // O-GEMM
#pragma unroll
        for (int ct = 0; ct < 8; ++ct) {
            acc[0][ct] = __builtin_amdgcn_mfma_f32_16x16x32_f16(hA[ct], pv0, acc[0][ct], 0, 0, 0);
            acc[1][ct] = __builtin_amdgcn_mfma_f32_16x16x32_f16(hA[ct], pv1, acc[1][ct], 0, 0, 0);
        }
#pragma unroll
        for (int ct = 0; ct < 8; ++ct) {
            acc[0][8 + ct] = __builtin_amdgcn_mfma_f32_16x16x32_f16(hB[ct], pv0, acc[0][8 + ct], 0, 0, 0);
            acc[1][8 + ct] = __builtin_amdgcn_mfma_f32_16x16x32_f16(hB[ct], pv1, acc[1][8 + ct], 0, 0, 0);
        }
        g1 = g1n;
        g2 = g2n;
    }

    // ---- cross-wave j-quarter reduction ----
    // lane holds O[c = 16ct + 4q + r][i = 16it + col]
    if (w == 0) {
#pragma unroll
        for (int it = 0; it < 2; ++it)
#pragma unroll
            for (int ct = 0; ct < 16; ++ct)
#pragma unroll
                for (int r = 0; r < 4; ++r)
                    red[(16 * ct + 4 * q + r) * 36 + 16 * it + col] = acc[it][ct][r];
    }
    __syncthreads();
    if (w != 0) {
#pragma unroll
        for (int it = 0; it < 2; ++it)
#pragma unroll
            for (int ct = 0; ct < 16; ++ct)
#pragma unroll
                for (int r = 0; r < 4; ++r)
                    atomicAdd(&red[(16 * ct + 4 * q + r) * 36 + 16 * it + col],
                              acc[it][ct][r]);
    }
    __syncthreads();

    // epilogue: out = O + x (nontemporal)
    const float* xb = x + (size_t)b * CC * NN;
    float* ob = out + (size_t)b * CC * NN;
    const int i4 = (tid & 7) * 4;
    const int cr = tid >> 3;   // 0..31
#pragma unroll
    for (int k = 0; k < 8; ++k) {
        int c = cr + 32 * k;
        size_t off = (size_t)c * NN + i0 + i4;
        f32x4 v = *(const f32x4*)&red[c * 36 + i4];
        f32x4 xv = __builtin_nontemporal_load((const f32x4*)(xb + off));
        v.x += xv.x; v.y += xv.y; v.z += xv.z; v.w += xv.w;
        __builtin_nontemporal_store(v, (f32x4*)(ob + off));
    }
}

// ---------------------------------------------------------------------------
extern "C" void kernel_launch(void* const* d_in, const int* in_sizes, int n_in,
                              void* d_out, int out_size, void* d_ws, size_t ws_size,
                              hipStream_t stream)
{
    const float* x  = (const float*)d_in[0];
    const float* fw = (const float*)d_in[1];
    const float* fb = (const float*)d_in[2];
    const float* gw = (const float*)d_in[3];
    const float* gb = (const float*)d_in[4];
    const float* hw = (const float*)d_in[5];
    const float* hb = (const float*)d_in[6];
    float* out = (float*)d_out;

    char* ws = (char*)d_ws;
    __half* xt = (__half*)(ws);                          // 16 MB (dead after proj)
    float*  l4 = (float*)(ws);                           // aliases xt: 512 KB
    __half* wf = (__half*)(ws + (size_t)16777216);
    __half* ft = (__half*)(ws + (size_t)17039360);
    __half* gt = (__half*)(ws + (size_t)19136512);
    __half* hm = (__half*)(ws + (size_t)21233664);
    float*  lv = (float*) (ws + (size_t)38010880);

    cvtw_kernel<<<dim3(320), dim3(256), 0, stream>>>(fw, gw, hw, wf);
    transpose_kernel<<<dim3(2048), dim3(256), 0, stream>>>(x, xt);
    proj_kernel<<<dim3(512), dim3(256), 0, stream>>>(xt, wf, fb, gb, hb, ft, gt, hm);
    pass1_kernel<<<dim3(2048), dim3(256), 0, stream>>>(ft, gt, l4);
    linv_kernel<<<dim3(128), dim3(256), 0, stream>>>(l4, lv);
    pass2_kernel<<<dim3(1024), dim3(256), 0, stream>>>(x, ft, gt, hm, lv, out);
}